// Round 2
// baseline (167.009 us; speedup 1.0000x reference)
//
#include <hip/hip_runtime.h>

#define NDAYS 250
#define NRESP 5
#define SCALING 12.0f

// Pi[d] = sum over flat k in [0,4N): w[k%N] * t_flat[k] * sigmoid(12*in_flat[k]), grouped by date[k%N]
// Reorganized per m = k%N: the 4 q-segments (k = q*N+m) share weights[m], date[m].
// Element index for (q,m): sample i_q = q*(N/4) + (m>>2), resp j = m&3 -> flat = i_q*NRESP + j.
__global__ __launch_bounds__(256) void pi_kernel(
    const float* __restrict__ inputs, const float* __restrict__ targets,
    const float* __restrict__ weights, const int* __restrict__ date,
    float* __restrict__ Pi, int n) {
    __shared__ float sPi[NDAYS];
    for (int i = threadIdx.x; i < NDAYS; i += blockDim.x) sPi[i] = 0.0f;
    __syncthreads();

    const int nq = n >> 2;  // N/4 (N divisible by 4)
    const long qstep = (long)nq * NRESP;
    const long stride = (long)gridDim.x * blockDim.x;
    for (long m = (long)blockIdx.x * blockDim.x + threadIdx.x; m < n; m += stride) {
        const int j = (int)(m & 3);
        const long base = (m >> 2) * NRESP + j;
        float acc = 0.0f;
        #pragma unroll
        for (int q = 0; q < 4; ++q) {
            const long idx = base + q * qstep;
            const float x = 1.0f / (1.0f + expf(-SCALING * inputs[idx]));
            acc += targets[idx] * x;
        }
        acc *= weights[m];
        const unsigned d = (unsigned)date[m];
        if (d < NDAYS) atomicAdd(&sPi[d], acc);
    }

    __syncthreads();
    for (int i = threadIdx.x; i < NDAYS; i += blockDim.x) {
        const float v = sPi[i];
        if (v != 0.0f) atomicAdd(&Pi[i], v);
    }
}

__global__ __launch_bounds__(64) void loss_kernel(const float* __restrict__ Pi,
                                                  float* __restrict__ out) {
    float s = 0.0f, q = 0.0f;
    for (int i = threadIdx.x; i < NDAYS; i += 64) {
        const float p = Pi[i];
        s += p;
        q += p * p;
    }
    #pragma unroll
    for (int off = 32; off > 0; off >>= 1) {
        s += __shfl_down(s, off);
        q += __shfl_down(q, off);
    }
    if (threadIdx.x == 0) {
        const float sumPi = s;
        const float loss = -1.0f * sumPi * fmaxf(sumPi, 0.0f) / q / (float)NDAYS;
        out[0] = loss;
    }
}

extern "C" void kernel_launch(void* const* d_in, const int* in_sizes, int n_in,
                              void* d_out, int out_size, void* d_ws, size_t ws_size,
                              hipStream_t stream) {
    const float* inputs  = (const float*)d_in[0];
    const float* targets = (const float*)d_in[1];
    const float* weights = (const float*)d_in[2];
    const int*   date    = (const int*)d_in[3];
    float* out = (float*)d_out;
    float* Pi  = (float*)d_ws;

    const int n = in_sizes[2];  // N (weights is [N])

    hipMemsetAsync(Pi, 0, NDAYS * sizeof(float), stream);
    pi_kernel<<<2048, 256, 0, stream>>>(inputs, targets, weights, date, Pi, n);
    loss_kernel<<<1, 64, 0, stream>>>(Pi, out);
}

// Round 4
// 125.751 us; speedup vs baseline: 1.3281x; 1.3281x over previous
//
#include <hip/hip_runtime.h>

#define NDAYS 250
#define NRESP 5
#define SCALING 12.0f
#define NB 1024      // pi_kernel blocks
#define T1 256       // pi_kernel threads/block
#define T2 1024      // finish_kernel threads
#define CHUNK 4      // row-chunks in finish (NB/CHUNK rows each)

// Pi[d] = sum over flat k in [0,4N): w[k%N] * t_flat[k] * sigmoid(12*in_flat[k]), by date[k%N].
// Per m = k%N: the 4 q-segments (k = q*N+m) share weights[m], date[m].
// (q,m) -> sample i = q*(N/4) + (m>>2), resp j = m&3 -> flat = i*NRESP + j.
// Each block accumulates into LDS Pi[250], then stores its partial row to ws (no atomics).
__global__ __launch_bounds__(T1) void pi_kernel(
    const float* __restrict__ inputs, const float* __restrict__ targets,
    const float* __restrict__ weights, const int* __restrict__ date,
    float* __restrict__ part, int n) {
    __shared__ float sPi[NDAYS];
    for (int i = threadIdx.x; i < NDAYS; i += T1) sPi[i] = 0.0f;
    __syncthreads();

    const int nq = n >> 2;                    // N/4
    const long qstep = (long)nq * NRESP;
    const long stride = (long)gridDim.x * T1;
    for (long m = (long)blockIdx.x * T1 + threadIdx.x; m < n; m += stride) {
        const int j = (int)(m & 3);
        const long base = (m >> 2) * NRESP + j;
        float acc = 0.0f;
        #pragma unroll
        for (int q = 0; q < 4; ++q) {
            const long idx = base + q * qstep;
            const float e = __expf(-SCALING * inputs[idx]);      // v_exp_f32 path
            const float x = __builtin_amdgcn_rcpf(1.0f + e);     // ~1 ulp, fine vs 2% headroom
            acc += targets[idx] * x;
        }
        acc *= weights[m];
        const unsigned d = (unsigned)date[m];
        if (d < NDAYS) atomicAdd(&sPi[d], acc);
    }

    __syncthreads();
    float* row = part + (size_t)blockIdx.x * NDAYS;
    for (int i = threadIdx.x; i < NDAYS; i += T1) row[i] = sPi[i];
}

// One block: reduce part[NB][250] -> Pi[250] -> loss. Coalesced: lane d reads part[r][d].
__global__ __launch_bounds__(T2) void finish_kernel(const float* __restrict__ part,
                                                    float* __restrict__ out) {
    __shared__ float red[CHUNK][256];
    __shared__ float ws_s[4], ws_q[4];
    const int t = threadIdx.x;
    const int d = t & 255;      // day (0..255; 250..255 dummy)
    const int c = t >> 8;       // chunk 0..3
    const int rows = NB / CHUNK;

    float acc = 0.0f;
    if (d < NDAYS) {
        const float* p = part + (size_t)c * rows * NDAYS + d;
        #pragma unroll 8
        for (int r = 0; r < rows; ++r) acc += p[(size_t)r * NDAYS];
    }
    red[c][d] = acc;
    __syncthreads();

    float s = 0.0f, q = 0.0f;
    if (t < 256) {
        const float p4 = red[0][t] + red[1][t] + red[2][t] + red[3][t];
        s = p4;
        q = p4 * p4;
    }
    // threads 0..255 are waves 0..3: per-wave shuffle reduce, then LDS combine
    #pragma unroll
    for (int off = 32; off > 0; off >>= 1) {
        s += __shfl_down(s, off);
        q += __shfl_down(q, off);
    }
    if (t < 256 && (t & 63) == 0) {
        ws_s[t >> 6] = s;
        ws_q[t >> 6] = q;
    }
    __syncthreads();
    if (t == 0) {
        const float sumPi = ws_s[0] + ws_s[1] + ws_s[2] + ws_s[3];
        const float sumPi2 = ws_q[0] + ws_q[1] + ws_q[2] + ws_q[3];
        out[0] = -1.0f * sumPi * fmaxf(sumPi, 0.0f) / sumPi2 / (float)NDAYS;
    }
}

extern "C" void kernel_launch(void* const* d_in, const int* in_sizes, int n_in,
                              void* d_out, int out_size, void* d_ws, size_t ws_size,
                              hipStream_t stream) {
    const float* inputs  = (const float*)d_in[0];
    const float* targets = (const float*)d_in[1];
    const float* weights = (const float*)d_in[2];
    const int*   date    = (const int*)d_in[3];
    float* out  = (float*)d_out;
    float* part = (float*)d_ws;   // NB*NDAYS floats = 1 MB

    const int n = in_sizes[2];    // N (weights is [N])

    pi_kernel<<<NB, T1, 0, stream>>>(inputs, targets, weights, date, part, n);
    finish_kernel<<<1, T2, 0, stream>>>(part, out);
}